// Round 4
// baseline (6573.191 us; speedup 1.0000x reference)
//
#include <hip/hip_runtime.h>
#include <stdint.h>

#define B      256
#define DIN    700
#define T      250
#define H      1024
#define DOUT   20
#define NW_IN  11     // u64 words for 700 input bits
#define NW_INP 12     // padded
#define NW_H   16     // u64 words for 1024 hidden bits
#define RPW    16     // rows per wave in currents_kernel

typedef unsigned long long u64;
typedef unsigned int u32;
typedef float vfloat4 __attribute__((ext_vector_type(4)));

__device__ __forceinline__ u64 rfl64(u64 x) {
    u32 lo = (u32)__builtin_amdgcn_readfirstlane((int)(u32)x);
    u32 hi = (u32)__builtin_amdgcn_readfirstlane((int)(u32)(x >> 32));
    return ((u64)hi << 32) | lo;
}

// ---------------- prep: transpose weights ----------------
// Wt[d][h] = W_hid[h][d];  WoT[h][o] = W_out[o][h]  (plain, natural packing)
__global__ void prep_weights(const float* __restrict__ W_hid,
                             const float* __restrict__ W_out,
                             float* __restrict__ Wt,
                             float* __restrict__ WoT) {
    int idx = blockIdx.x * 256 + threadIdx.x;
    if (blockIdx.x < 2800) {                 // 700*1024 = 716800 = 2800*256
        int d = idx >> 10;
        int h = idx & 1023;
        Wt[idx] = W_hid[h * DIN + d];
    } else {
        int i = idx - 2800 * 256;            // 0..20479
        int h = i / DOUT;
        int o = i - h * DOUT;
        WoT[i] = W_out[o * H + h];
    }
}

// ---------------- prep: bitpack spikes ----------------
__global__ void prep_bits(const float* __restrict__ spk,
                          u64* __restrict__ bits) {
    int b  = blockIdx.x >> 2;
    int wc = blockIdx.x & 3;
    int t  = threadIdx.x;
    if (t >= T) return;
    int w0 = wc * 3;
    int w1 = (wc == 3) ? NW_IN : w0 + 3;
    const float* base = spk + (size_t)b * DIN * T + t;
    for (int w = w0; w < w1; ++w) {
        u64 m = 0;
#pragma unroll
        for (int j = 0; j < 64; ++j) {
            int d = (w << 6) + j;
            if (d < DIN) {
                float x = base[(size_t)d * T];
                m |= (u64)(x > 0.5f) << j;
            }
        }
        bits[((size_t)b * T + t) * NW_INP + w] = m;
    }
}

// ---------------- S1: input currents, 16 rows/wave register reuse ----------------
// Wave = 16 rows x 256-h slice (lane holds 4 h, float4). Per d-word: masks ->
// SGPR, walk ctz over OR (ascending d = exact reference sum order per row),
// load Wt[d] slice ONCE, add into active rows via uniform scalar branches.
__global__ void __launch_bounds__(256)
currents_kernel(const u64* __restrict__ bits,   // chunk-local [rows][12]
                const float* __restrict__ Wt,   // [700][1024]
                float* __restrict__ I) {        // chunk-local [rows][1024]
    int slice = blockIdx.x & 3;
    int rg    = blockIdx.x >> 2;
    int wv    = threadIdx.x >> 6;
    int lane  = threadIdx.x & 63;
    int row0  = rg * 64 + wv * RPW;
    int hbase = slice * 256 + lane * 4;

    vfloat4 acc[RPW];
#pragma unroll
    for (int r = 0; r < RPW; ++r) acc[r] = (vfloat4){0.0f, 0.0f, 0.0f, 0.0f};

    const u64* brow = bits + (size_t)row0 * NW_INP;

#pragma unroll 1
    for (int w = 0; w < NW_IN; ++w) {
        u64 m[RPW];
        u64 mor = 0;
#pragma unroll
        for (int r = 0; r < RPW; ++r) {
            m[r] = rfl64(brow[r * NW_INP + w]);
            mor |= m[r];
        }
        const float* wrow = Wt + (size_t)(w << 6) * H + hbase;
        while (mor) {
            int j = __builtin_ctzll(mor);
            mor &= mor - 1;
            vfloat4 wt = *(const vfloat4*)(wrow + (size_t)j * H);
#pragma unroll
            for (int r = 0; r < RPW; ++r) {
                if ((m[r] >> j) & 1ull) acc[r] += wt;
            }
        }
    }

#pragma unroll
    for (int r = 0; r < RPW; ++r)
        __builtin_nontemporal_store(acc[r], (vfloat4*)(I + (size_t)(row0 + r) * H + hbase));
}

// ---------------- S2: hidden membrane scan + spike ballot ----------------
// blockIdx = b_local*4 + slice; thread h = slice*256 + tid.
// Ballot packing is natural: hsbits word = h>>6, bit = h&63.
__global__ void __launch_bounds__(256)
scan_kernel(const float* __restrict__ I,      // chunk-local
            const float* __restrict__ hs0,    // pre-offset to chunk
            const float* __restrict__ hv0,    // pre-offset to chunk
            u64* __restrict__ hsbits) {       // pre-offset to chunk
    int b     = blockIdx.x >> 2;   // local b
    int slice = blockIdx.x & 3;
    int tid   = threadIdx.x;
    int wv    = tid >> 6;
    int lane  = tid & 63;
    int h     = slice * 256 + tid;

    float keep = hv0[b * H + h] * 0.5f * (1.0f - hs0[b * H + h]);
    const float* ip = I + (size_t)b * T * H + h;
    u64* hp = hsbits + (size_t)b * T * NW_H + slice * 4 + wv;

#pragma unroll 5
    for (int t = 0; t < T; ++t) {
        float v = keep + ip[(size_t)t * H];
        bool s = v > 0.5f;
        keep = s ? 0.0f : v * 0.5f;
        u64 bal = __ballot(s);
        if (lane == 0) hp[(size_t)t * NW_H] = bal;
    }
}

// ---------------- output currents: Iout[b*T+t][o] ----------------
// one wave per row (b,t); index = w*64+lane maps directly to h.
__global__ void __launch_bounds__(256)
out_currents(const u64* __restrict__ hsbits,
             const float* __restrict__ WoT,
             float* __restrict__ Iout) {
    __shared__ int lidx[4][2][256];

    int wv   = threadIdx.x >> 6;
    int lane = threadIdx.x & 63;
    int row  = blockIdx.x * 4 + wv;   // < 64000 exactly

    const u64* wp = hsbits + (size_t)row * NW_H;

    float acc = 0.0f;
#pragma unroll
    for (int g = 0; g < 4; ++g) {
        u64 w[4];
#pragma unroll
        for (int k = 0; k < 4; ++k) w[k] = wp[g * 4 + k];

        int base[5];
        base[0] = 0;
#pragma unroll
        for (int k = 0; k < 4; ++k) base[k + 1] = base[k] + __popcll(w[k]);
        int n = base[4];

        int buf = g & 1;
#pragma unroll
        for (int k = 0; k < 4; ++k) {
            u64 m = w[k];
            if ((m >> lane) & 1ull) {
                int pos = base[k] + __popcll(m & ((lane == 63) ? 0x7fffffffffffffffull
                                                               : ((1ull << lane) - 1ull)));
                lidx[wv][buf][pos] = ((g * 4 + k) << 6) + lane;
            }
        }
        __syncthreads();

        const int* il = lidx[wv][buf];
        int i = 0;
        for (; i + 4 <= n; i += 4) {
            int j0 = il[i + 0], j1 = il[i + 1], j2 = il[i + 2], j3 = il[i + 3];
            if (lane < DOUT) {
                float v0 = WoT[(size_t)j0 * DOUT + lane];
                float v1 = WoT[(size_t)j1 * DOUT + lane];
                float v2 = WoT[(size_t)j2 * DOUT + lane];
                float v3 = WoT[(size_t)j3 * DOUT + lane];
                acc += v0; acc += v1; acc += v2; acc += v3;
            }
        }
        for (; i < n; ++i) {
            if (lane < DOUT) acc += WoT[(size_t)il[i] * DOUT + lane];
        }
    }
    if (lane < DOUT) Iout[(size_t)row * DOUT + lane] = acc;
}

// ---------------- output scan + spike count ----------------
__global__ void out_scan(const float* __restrict__ Iout,
                         const float* __restrict__ os0,
                         const float* __restrict__ ov0,
                         float* __restrict__ outp) {
    int idx = blockIdx.x * 256 + threadIdx.x;
    if (idx >= B * DOUT) return;
    int b = idx / DOUT;
    int o = idx - b * DOUT;

    float ov = ov0[idx];
    float os = os0[idx];
    float keep = ov * 0.5f * (1.0f - os);
    float cnt = 0.0f;
    const float* ip = Iout + (size_t)b * T * DOUT + o;
#pragma unroll 5
    for (int t = 0; t < T; ++t) {
        float v = keep + ip[(size_t)t * DOUT];
        float s = (v > 0.5f) ? 1.0f : 0.0f;
        cnt += s;
        keep = v * 0.5f * (1.0f - s);
    }
    outp[idx] = cnt;
}

extern "C" void kernel_launch(void* const* d_in, const int* in_sizes, int n_in,
                              void* d_out, int out_size, void* d_ws, size_t ws_size,
                              hipStream_t stream) {
    const float* spike = (const float*)d_in[0];   // [256][700][250]
    const float* W_hid = (const float*)d_in[1];   // [1024][700]
    const float* W_out = (const float*)d_in[2];   // [20][1024]
    const float* hs0   = (const float*)d_in[3];   // [256][1024]
    const float* hv0   = (const float*)d_in[4];
    const float* os0   = (const float*)d_in[5];   // [256][20]
    const float* ov0   = (const float*)d_in[6];
    float* outp = (float*)d_out;                  // [256][20]

    char* ws = (char*)d_ws;
    float* Wt     = (float*)(ws);                 // 716800*4   = 2,867,200
    float* WoT    = (float*)(ws + 2867200);       // 20480*4    =    81,920
    u64*   bits   = (u64*)  (ws + 2949120);       // 64000*12*8 = 6,144,000
    u64*   hsbits = (u64*)  (ws + 9093120);       // 64000*16*8 = 8,192,000
    float* Iout   = (float*)(ws + 17285120);      // 64000*20*4 = 5,120,000
    float* Ibuf   = (float*)(ws + 22405120);      // bchunk * 250*1024*4

    // Largest b-chunk whose I buffer fits the workspace (deterministic in ws_size).
    int bchunk = 256;
    while (bchunk > 32 &&
           (size_t)22405120 + (size_t)bchunk * 1024000ull > ws_size)
        bchunk >>= 1;

    prep_weights<<<2880, 256, 0, stream>>>(W_hid, W_out, Wt, WoT);
    prep_bits<<<1024, 256, 0, stream>>>(spike, bits);

    for (int b0 = 0; b0 < B; b0 += bchunk) {
        int rows = bchunk * T;                       // multiple of 64 for bchunk>=32
        currents_kernel<<<(rows / 64) * 4, 256, 0, stream>>>(
            bits + (size_t)b0 * T * NW_INP, Wt, Ibuf);
        scan_kernel<<<bchunk * 4, 256, 0, stream>>>(
            Ibuf, hs0 + (size_t)b0 * H, hv0 + (size_t)b0 * H,
            hsbits + (size_t)b0 * T * NW_H);
    }

    out_currents<<<16000, 256, 0, stream>>>(hsbits, WoT, Iout);
    out_scan<<<20, 256, 0, stream>>>(Iout, os0, ov0, outp);
}

// Round 5
// 1352.348 us; speedup vs baseline: 4.8606x; 4.8606x over previous
//
#include <hip/hip_runtime.h>
#include <stdint.h>

#define B       256
#define DIN     700
#define T       250
#define H       1024
#define DOUT    20
#define NW_IN   11     // u64 words for 700 input bits
#define NW_INP  12     // padded
#define NW_H    16     // u64 words for 1024 hidden bits
#define LSTRIDE 144    // list entries per row (mult of 4; 70 mean + 9 sigma safe)
#define SLICE   16     // h per block in currents_slice
#define LDS_STRIDE 17  // floats per d-row in LDS (16 + 1 pad)
#define ZPAD    (700 * LDS_STRIDE * 4)   // byte offset of LDS zero row
#define ROWCHUNK 8000  // rows per block chunk in currents_slice

typedef unsigned long long u64;
typedef unsigned int u32;

// ---------------- prep: transpose W_out only ----------------
// WoT[h][o] = W_out[o][h]  (natural hidden-bit packing)
__global__ void prep_weights(const float* __restrict__ W_out,
                             float* __restrict__ WoT) {
    int i = blockIdx.x * 256 + threadIdx.x;   // < 20480
    int h = i / DOUT;
    int o = i - h * DOUT;
    WoT[i] = W_out[o * H + h];
}

// ---------------- prep: bitpack spikes ----------------
__global__ void prep_bits(const float* __restrict__ spk,
                          u64* __restrict__ bits) {
    int b  = blockIdx.x >> 2;
    int wc = blockIdx.x & 3;
    int t  = threadIdx.x;
    if (t >= T) return;
    int w0 = wc * 3;
    int w1 = (wc == 3) ? NW_IN : w0 + 3;
    const float* base = spk + (size_t)b * DIN * T + t;
    for (int w = w0; w < w1; ++w) {
        u64 m = 0;
#pragma unroll
        for (int j = 0; j < 64; ++j) {
            int d = (w << 6) + j;
            if (d < DIN) {
                float x = base[(size_t)d * T];
                m |= (u64)(x > 0.5f) << j;
            }
        }
        bits[((size_t)b * T + t) * NW_INP + w] = m;
    }
}

// ---------------- expand: bits -> LDS-byte-offset lists ----------------
// one wave per (b,t) row. Entry = d * LDS_STRIDE * 4 (pre-scaled LDS byte
// offset), ascending d; padded to LSTRIDE with the zero-row offset.
__global__ void __launch_bounds__(256)
expand_kernel(const u64* __restrict__ bits,
              u32* __restrict__ lists,
              u32* __restrict__ ncnt) {
    int wv   = threadIdx.x >> 6;
    int lane = threadIdx.x & 63;
    int row  = blockIdx.x * 4 + wv;          // 16000 blocks -> 64000 rows
    const u64* wp = bits + (size_t)row * NW_INP;
    u32* lp = lists + (size_t)row * LSTRIDE;

    u64 lmask = (lane == 63) ? 0x7fffffffffffffffull : ((1ull << lane) - 1ull);
    u32 base = 0;
#pragma unroll
    for (int w = 0; w < NW_IN; ++w) {
        u64 m = wp[w];
        if ((m >> lane) & 1ull) {
            u32 pos = base + (u32)__popcll(m & lmask);
            if (pos < LSTRIDE) lp[pos] = (u32)((w << 6) + lane) * (LDS_STRIDE * 4);
        }
        base += (u32)__popcll(m);
    }
    u32 n = base < LSTRIDE ? base : LSTRIDE;
    for (u32 pos = n + lane; pos < LSTRIDE; pos += 64) lp[pos] = ZPAD;
    if (lane == 0) ncnt[row] = n;
}

// ---------------- S1: input currents, LDS-staged weight slice ----------------
// Block = 16-h slice x 8000-row chunk. Stage W_hid[h0..h0+15][0..699] into
// LDS (stride 17, + zero row), then wave = 4 rows x 16 h: per list entry
// 1 v_add + 1 ds_read_b32 + 1 v_add acc. Ascending-d sum order (bit-exact).
__global__ void __launch_bounds__(1024, 8)
currents_slice(const float* __restrict__ W_hid,
               const u32* __restrict__ lists,  // pre-offset to chunk
               const u32* __restrict__ ncnt,   // pre-offset to chunk
               float* __restrict__ I) {        // chunk-local [rows][1024]
    __shared__ float wlds[701 * LDS_STRIDE];   // 47,668 B

    int slice = blockIdx.x & 63;
    int chunk = blockIdx.x >> 6;
    int h0    = slice * SLICE;
    int tid   = threadIdx.x;

    // stage: W_hid[(h0+j)*700 + d] = W_hid[h0*700 + i] with d=i%700, j=i/700
    const float* wsrc = W_hid + h0 * DIN;
    for (int i = tid; i < SLICE * DIN; i += 1024) {
        int j = i / DIN;
        int d = i - j * DIN;
        wlds[d * LDS_STRIDE + j] = wsrc[i];
    }
    if (tid < SLICE) wlds[700 * LDS_STRIDE + tid] = 0.0f;
    __syncthreads();

    const char* wb = (const char*)wlds;
    int wv   = tid >> 6;
    int lane = tid & 63;
    int r_in = lane >> 4;          // 0..3: row within wave
    int j4   = (lane & 15) << 2;   // h byte offset within slice

    int rbase = chunk * ROWCHUNK;

    for (int rb = wv * 4; rb < ROWCHUNK; rb += 64) {
        int row = rbase + rb + r_in;
        int n = ncnt[row];
        int m1   = max(n, __shfl_xor(n, 16));
        int maxn = max(m1, __shfl_xor(m1, 32));
        int maxk = (maxn + 3) & ~3;

        const u32* lp = lists + (size_t)row * LSTRIDE;
        float acc = 0.0f;
        for (int k = 0; k < maxk; k += 4) {
            uint4 e = *(const uint4*)(lp + k);
            acc += *(const float*)(wb + (e.x + j4));
            acc += *(const float*)(wb + (e.y + j4));
            acc += *(const float*)(wb + (e.z + j4));
            acc += *(const float*)(wb + (e.w + j4));
        }
        __builtin_nontemporal_store(acc, I + (size_t)row * H + h0 + (lane & 15));
    }
}

// ---------------- S2: hidden membrane scan + spike ballot ----------------
__global__ void __launch_bounds__(256)
scan_kernel(const float* __restrict__ I,      // chunk-local
            const float* __restrict__ hs0,    // pre-offset to chunk
            const float* __restrict__ hv0,    // pre-offset to chunk
            u64* __restrict__ hsbits) {       // pre-offset to chunk
    int b     = blockIdx.x >> 2;   // local b
    int slice = blockIdx.x & 3;
    int tid   = threadIdx.x;
    int wv    = tid >> 6;
    int lane  = tid & 63;
    int h     = slice * 256 + tid;

    float keep = hv0[b * H + h] * 0.5f * (1.0f - hs0[b * H + h]);
    const float* ip = I + (size_t)b * T * H + h;
    u64* hp = hsbits + (size_t)b * T * NW_H + slice * 4 + wv;

#pragma unroll 5
    for (int t = 0; t < T; ++t) {
        float v = keep + ip[(size_t)t * H];
        bool s = v > 0.5f;
        keep = s ? 0.0f : v * 0.5f;
        u64 bal = __ballot(s);
        if (lane == 0) hp[(size_t)t * NW_H] = bal;
    }
}

// ---------------- output currents: Iout[b*T+t][o] ----------------
__global__ void __launch_bounds__(256)
out_currents(const u64* __restrict__ hsbits,
             const float* __restrict__ WoT,
             float* __restrict__ Iout) {
    __shared__ int lidx[4][2][256];

    int wv   = threadIdx.x >> 6;
    int lane = threadIdx.x & 63;
    int row  = blockIdx.x * 4 + wv;   // < 64000 exactly

    const u64* wp = hsbits + (size_t)row * NW_H;

    float acc = 0.0f;
#pragma unroll
    for (int g = 0; g < 4; ++g) {
        u64 w[4];
#pragma unroll
        for (int k = 0; k < 4; ++k) w[k] = wp[g * 4 + k];

        int base[5];
        base[0] = 0;
#pragma unroll
        for (int k = 0; k < 4; ++k) base[k + 1] = base[k] + __popcll(w[k]);
        int n = base[4];

        int buf = g & 1;
#pragma unroll
        for (int k = 0; k < 4; ++k) {
            u64 m = w[k];
            if ((m >> lane) & 1ull) {
                int pos = base[k] + __popcll(m & ((lane == 63) ? 0x7fffffffffffffffull
                                                               : ((1ull << lane) - 1ull)));
                lidx[wv][buf][pos] = ((g * 4 + k) << 6) + lane;
            }
        }
        __syncthreads();

        const int* il = lidx[wv][buf];
        int i = 0;
        for (; i + 4 <= n; i += 4) {
            int j0 = il[i + 0], j1 = il[i + 1], j2 = il[i + 2], j3 = il[i + 3];
            if (lane < DOUT) {
                float v0 = WoT[(size_t)j0 * DOUT + lane];
                float v1 = WoT[(size_t)j1 * DOUT + lane];
                float v2 = WoT[(size_t)j2 * DOUT + lane];
                float v3 = WoT[(size_t)j3 * DOUT + lane];
                acc += v0; acc += v1; acc += v2; acc += v3;
            }
        }
        for (; i < n; ++i) {
            if (lane < DOUT) acc += WoT[(size_t)il[i] * DOUT + lane];
        }
    }
    if (lane < DOUT) Iout[(size_t)row * DOUT + lane] = acc;
}

// ---------------- output scan + spike count ----------------
__global__ void out_scan(const float* __restrict__ Iout,
                         const float* __restrict__ os0,
                         const float* __restrict__ ov0,
                         float* __restrict__ outp) {
    int idx = blockIdx.x * 256 + threadIdx.x;
    if (idx >= B * DOUT) return;
    int b = idx / DOUT;
    int o = idx - b * DOUT;

    float ov = ov0[idx];
    float os = os0[idx];
    float keep = ov * 0.5f * (1.0f - os);
    float cnt = 0.0f;
    const float* ip = Iout + (size_t)b * T * DOUT + o;
#pragma unroll 5
    for (int t = 0; t < T; ++t) {
        float v = keep + ip[(size_t)t * DOUT];
        float s = (v > 0.5f) ? 1.0f : 0.0f;
        cnt += s;
        keep = v * 0.5f * (1.0f - s);
    }
    outp[idx] = cnt;
}

extern "C" void kernel_launch(void* const* d_in, const int* in_sizes, int n_in,
                              void* d_out, int out_size, void* d_ws, size_t ws_size,
                              hipStream_t stream) {
    const float* spike = (const float*)d_in[0];   // [256][700][250]
    const float* W_hid = (const float*)d_in[1];   // [1024][700]
    const float* W_out = (const float*)d_in[2];   // [20][1024]
    const float* hs0   = (const float*)d_in[3];   // [256][1024]
    const float* hv0   = (const float*)d_in[4];
    const float* os0   = (const float*)d_in[5];   // [256][20]
    const float* ov0   = (const float*)d_in[6];
    float* outp = (float*)d_out;                  // [256][20]

    char* ws = (char*)d_ws;
    float* WoT    = (float*)(ws);                 // 20480*4      =    81,920
    u64*   bits   = (u64*)  (ws + 81920);         // 64000*12*8   = 6,144,000
    u32*   ncnt   = (u32*)  (ws + 6225920);       // 64000*4      =   256,000
    u32*   lists  = (u32*)  (ws + 6481920);       // 64000*144*4  = 36,864,000
    u64*   hsbits = (u64*)  (ws + 43345920);      // 64000*16*8   = 8,192,000
    float* Iout   = (float*)(ws + 51537920);      // 64000*20*4   = 5,120,000
    float* Ibuf   = (float*)(ws + 56657920);      // bchunk*250*1024*4

    // Largest b-chunk whose I buffer fits the workspace (deterministic in ws_size).
    int bchunk = 256;
    while (bchunk > 32 &&
           (size_t)56657920 + (size_t)bchunk * 1024000ull > ws_size)
        bchunk >>= 1;

    prep_weights<<<80, 256, 0, stream>>>(W_out, WoT);
    prep_bits<<<1024, 256, 0, stream>>>(spike, bits);
    expand_kernel<<<16000, 256, 0, stream>>>(bits, lists, ncnt);

    for (int b0 = 0; b0 < B; b0 += bchunk) {
        int rows = bchunk * T;                     // multiple of ROWCHUNK for bchunk>=32
        currents_slice<<<64 * (rows / ROWCHUNK), 1024, 0, stream>>>(
            W_hid,
            lists + (size_t)(b0 * T) * LSTRIDE,
            ncnt + (size_t)(b0 * T),
            Ibuf);
        scan_kernel<<<bchunk * 4, 256, 0, stream>>>(
            Ibuf, hs0 + (size_t)b0 * H, hv0 + (size_t)b0 * H,
            hsbits + (size_t)b0 * T * NW_H);
    }

    out_currents<<<16000, 256, 0, stream>>>(hsbits, WoT, Iout);
    out_scan<<<20, 256, 0, stream>>>(Iout, os0, ov0, outp);
}